// Round 2
// baseline (1637.951 us; speedup 1.0000x reference)
//
#include <hip/hip_runtime.h>
#include <hip/hip_bf16.h>
#include <math.h>

// Problem constants
#define BB   8
#define CIN  512
#define HH   64
#define WW   64
#define COUT 128
#define HW   4096        // HH*WW
#define PIX  32768       // BB*HW
#define MAXOFF 16.0f     // min(H,W)//4

// Workspace layout (float offsets)
#define OFF_XT      0ull            // x transposed NHWC: 8*4096*512        = 16,777,216
#define OFF_PARTIAL 16777216ull     // conv27 partials [4][8][27][4096]     =  3,538,944
#define OFF_PWT     20316160ull     // proj_w  [tap][c][oc] 9*512*128       =    589,824
#define OFF_W27T    20905984ull     // off/mod w [c][tap][28] 512*252       =    129,024
#define OFF_STATS   21035008ull     // mean[128], rstd[128]
// total = 21,035,264 floats = 84.1 MB

// ---------------------------------------------------------------- transpose
// x [b][c][p] -> xt [b][p][c]   (p = h*64+w)
__global__ __launch_bounds__(256) void k_transpose(const float* __restrict__ x,
                                                   float* __restrict__ xt) {
    __shared__ float tile[32][33];
    int b  = blockIdx.z;
    int p0 = blockIdx.x * 32;
    int c0 = blockIdx.y * 32;
    int tx = threadIdx.x, ty = threadIdx.y;          // 32 x 8
    const float* src = x  + (size_t)b * CIN * HW;
    float*       dst = xt + (size_t)b * HW  * CIN;
    #pragma unroll
    for (int i = 0; i < 4; ++i)
        tile[ty + i*8][tx] = src[(size_t)(c0 + ty + i*8) * HW + p0 + tx];
    __syncthreads();
    #pragma unroll
    for (int i = 0; i < 4; ++i)
        dst[(size_t)(p0 + ty + i*8) * CIN + c0 + tx] = tile[tx][ty + i*8];
}

// ---------------------------------------------------------------- weight repack
__global__ void k_prep_w(const float* __restrict__ proj_w,
                         const float* __restrict__ off_w,
                         const float* __restrict__ mod_w,
                         float* __restrict__ ws) {
    float* pwt  = ws + OFF_PWT;   // [tap][c][oc]
    float* w27t = ws + OFF_W27T;  // [c][tap][28] (slot 27 = zeroed pad)
    const int total = 589824 + 129024;
    for (int i = blockIdx.x * blockDim.x + threadIdx.x; i < total;
         i += gridDim.x * blockDim.x) {
        if (i < 589824) {
            int tap = i / (512 * 128);
            int r   = i % (512 * 128);
            int c = r / 128, oc = r % 128;
            pwt[i] = proj_w[(size_t)oc * 4608 + c * 9 + tap];
        } else {
            int j = i - 589824;          // index into [c][tap][28]
            int c = j / 252, r = j % 252;
            int tap = r / 28, oc = r % 28;
            float v = 0.f;
            if (oc < 18)      v = off_w[(size_t)oc * 4608 + c * 9 + tap];
            else if (oc < 27) v = mod_w[(size_t)(oc - 18) * 4608 + c * 9 + tap];
            w27t[c * 252 + tap * 28 + oc] = v;   // oc==27 -> 0 pad
        }
    }
}

// ---------------------------------------------------------------- offset/modulator conv
// thread = one pixel, computes all 27 output channels over a 128-channel c-slice.
// partial [csub][b][27][hw]
__global__ __launch_bounds__(256) void k_conv27(const float* __restrict__ x,
                                                const float* __restrict__ w27t,
                                                float* __restrict__ partial) {
    int tid  = threadIdx.x;
    int p    = blockIdx.x * 256 + tid;
    int csub = blockIdx.y;
    int b  = p >> 12;
    int hw = p & 4095;
    int h  = hw >> 6, w = hw & 63;

    float acc[28];
    #pragma unroll
    for (int i = 0; i < 28; ++i) acc[i] = 0.f;

    const float* xb = x + (size_t)b * CIN * HW;
    int c0 = csub * 128;
    for (int c = c0; c < c0 + 128; ++c) {
        float xv[9];
        #pragma unroll
        for (int t = 0; t < 9; ++t) {
            int yy = h + t / 3 - 1, xx = w + t % 3 - 1;
            bool v = (yy >= 0) && (yy < 64) && (xx >= 0) && (xx < 64);
            xv[t] = v ? xb[(size_t)c * HW + yy * 64 + xx] : 0.f;
        }
        const float4* wp = (const float4*)(w27t + c * 252); // uniform -> s_load
        #pragma unroll
        for (int t = 0; t < 9; ++t) {
            #pragma unroll
            for (int q = 0; q < 7; ++q) {
                float4 wv = wp[t * 7 + q];
                acc[q*4+0] += xv[t] * wv.x;
                acc[q*4+1] += xv[t] * wv.y;
                acc[q*4+2] += xv[t] * wv.z;
                acc[q*4+3] += xv[t] * wv.w;   // q==6,l==3 -> pad acc[27], never stored
            }
        }
    }
    float* dst = partial + ((size_t)(csub * 8 + b) * 27) * HW + hw;
    #pragma unroll
    for (int oc = 0; oc < 27; ++oc) dst[(size_t)oc * HW] = acc[oc];
}

// ---------------------------------------------------------------- fused deformable sample + projection
// block = one (b,h) row: 64 px x 128 oc output tile. Writes pre-BN to d_out.
// NOTE: proj_b omitted on purpose — a per-channel constant cancels exactly in BN.
__global__ __launch_bounds__(256) void k_deform_proj(const float* __restrict__ xt,
                                                     const float* __restrict__ partial,
                                                     const float* __restrict__ off_b,
                                                     const float* __restrict__ mod_b,
                                                     const float* __restrict__ pwt,
                                                     float* __restrict__ out) {
    __shared__ int    sy0[9][64];
    __shared__ int    sx0[9][64];
    __shared__ float4 sw4[9][64];
    __shared__ __align__(16) float s_tile[64 * 66];   // [cc][px] padded stride 66
    __shared__ __align__(16) float w_tile[64 * 128];  // [cc][oc]

    int tid = threadIdx.x;
    int bh  = blockIdx.x;
    int b = bh >> 6, h = bh & 63;

    // ---- stage per-(pixel,tap) sampling params
    for (int i = tid; i < 576; i += 256) {
        int k = i / 64, px = i % 64;
        int hw = h * 64 + px;
        float oy = off_b[2 * k], ox = off_b[2 * k + 1], om = mod_b[k];
        #pragma unroll
        for (int s = 0; s < 4; ++s) {
            const float* pp = partial + ((size_t)(s * 8 + b) * 27) * HW + hw;
            oy += pp[(size_t)(2 * k)     * HW];
            ox += pp[(size_t)(2 * k + 1) * HW];
            om += pp[(size_t)(18 + k)    * HW];
        }
        oy = fminf(fmaxf(oy, -MAXOFF), MAXOFF);
        ox = fminf(fmaxf(ox, -MAXOFF), MAXOFF);
        float m = 2.f / (1.f + expf(-om));
        float py  = (float)h  + (float)(k / 3) - 1.f + oy;
        float pxf = (float)px + (float)(k % 3) - 1.f + ox;
        float y0f = floorf(py), x0f = floorf(pxf);
        float fy = py - y0f, fx = pxf - x0f;
        sy0[k][px] = (int)y0f;
        sx0[k][px] = (int)x0f;
        sw4[k][px] = make_float4((1.f - fy) * (1.f - fx) * m,
                                 (1.f - fy) * fx         * m,
                                 fy         * (1.f - fx) * m,
                                 fy         * fx         * m);
    }
    __syncthreads();

    float acc0[16], acc1[16];
    #pragma unroll
    for (int j = 0; j < 16; ++j) { acc0[j] = 0.f; acc1[j] = 0.f; }
    int px2 = (tid & 31) * 2;
    int ocg = tid >> 5;

    const float* xtb = xt + (size_t)b * HW * CIN;

    for (int k = 0; k < 9; ++k) {
        for (int ch = 0; ch < 8; ++ch) {
            int cbase = ch * 64;
            __syncthreads();   // protect tiles from previous iteration's readers
            // ---- stage sampled tile s_tile[c][px]
            #pragma unroll
            for (int pass = 0; pass < 16; ++pass) {
                int i   = pass * 256 + tid;
                int c_l = i & 63, pxx = i >> 6;
                int iy0 = sy0[k][pxx], ix0 = sx0[k][pxx];
                float4 wv = sw4[k][pxx];
                const float* base = xtb + cbase + c_l;
                float v00 = 0.f, v01 = 0.f, v10 = 0.f, v11 = 0.f;
                bool y0v = (unsigned)iy0       < 64u, y1v = (unsigned)(iy0 + 1) < 64u;
                bool x0v = (unsigned)ix0       < 64u, x1v = (unsigned)(ix0 + 1) < 64u;
                if (y0v && x0v) v00 = base[(size_t)(iy0 * 64 + ix0)       * 512];
                if (y0v && x1v) v01 = base[(size_t)(iy0 * 64 + ix0 + 1)   * 512];
                if (y1v && x0v) v10 = base[(size_t)((iy0 + 1) * 64 + ix0) * 512];
                if (y1v && x1v) v11 = base[(size_t)((iy0 + 1) * 64 + ix0 + 1) * 512];
                s_tile[c_l * 66 + pxx] = wv.x * v00 + wv.y * v01 + wv.z * v10 + wv.w * v11;
            }
            // ---- stage weight tile w_tile[c][oc]
            {
                const float4* src  = (const float4*)(pwt + ((size_t)k * 512 + cbase) * 128);
                float4*       dst4 = (float4*)w_tile;
                #pragma unroll
                for (int pass = 0; pass < 8; ++pass)
                    dst4[pass * 256 + tid] = src[pass * 256 + tid];
            }
            __syncthreads();
            // ---- GEMM micro-tile: 2 px x 16 oc per thread
            #pragma unroll 8
            for (int cc = 0; cc < 64; ++cc) {
                float2 s2 = *(const float2*)&s_tile[cc * 66 + px2];
                const float4* wt = (const float4*)&w_tile[cc * 128 + ocg * 16];
                #pragma unroll
                for (int q = 0; q < 4; ++q) {
                    float4 wv = wt[q];
                    acc0[q*4+0] += s2.x * wv.x;  acc1[q*4+0] += s2.y * wv.x;
                    acc0[q*4+1] += s2.x * wv.y;  acc1[q*4+1] += s2.y * wv.y;
                    acc0[q*4+2] += s2.x * wv.z;  acc1[q*4+2] += s2.y * wv.z;
                    acc0[q*4+3] += s2.x * wv.w;  acc1[q*4+3] += s2.y * wv.w;
                }
            }
        }
    }
    // ---- write pre-BN output [b][oc][h][px]
    float* ob = out + (((size_t)b * COUT) * 64 + h) * 64 + px2;
    #pragma unroll
    for (int j = 0; j < 16; ++j) {
        int oc = ocg * 16 + j;
        *(float2*)&ob[(size_t)oc * HW] = make_float2(acc0[j], acc1[j]);
    }
}

// ---------------------------------------------------------------- BN statistics (per channel)
__global__ __launch_bounds__(256) void k_bn_stats(const float* __restrict__ pre,
                                                  float* __restrict__ stats) {
    int oc  = blockIdx.x;
    int tid = threadIdx.x;
    float s = 0.f, ss = 0.f;
    for (int i = tid; i < PIX; i += 256) {
        int b = i >> 12, hw = i & 4095;
        float v = pre[((size_t)(b * COUT + oc)) * HW + hw];
        s += v; ss += v * v;
    }
    #pragma unroll
    for (int off = 32; off > 0; off >>= 1) {
        s  += __shfl_down(s,  off, 64);
        ss += __shfl_down(ss, off, 64);
    }
    __shared__ float red[8];
    int wid = tid >> 6, lane = tid & 63;
    if (lane == 0) { red[wid] = s; red[4 + wid] = ss; }
    __syncthreads();
    if (tid == 0) {
        float S  = red[0] + red[1] + red[2] + red[3];
        float SS = red[4] + red[5] + red[6] + red[7];
        float mean = S / (float)PIX;
        float var  = SS / (float)PIX - mean * mean;
        stats[oc]       = mean;
        stats[128 + oc] = rsqrtf(var + 1e-5f);
    }
}

// ---------------------------------------------------------------- BN apply + exact GELU (in-place on d_out)
__global__ __launch_bounds__(256) void k_bn_gelu(float* __restrict__ out,
                                                 const float* __restrict__ stats,
                                                 const float* __restrict__ gamma,
                                                 const float* __restrict__ beta) {
    const int n4 = (BB * COUT * HW) / 4;   // 1,048,576 float4
    const float is2 = 0.70710678118654752f;
    for (int i = blockIdx.x * blockDim.x + threadIdx.x; i < n4;
         i += gridDim.x * blockDim.x) {
        int oc = (i >> 10) & 127;          // 1024 float4 per (b,oc) plane
        float g  = gamma[oc] * stats[128 + oc];
        float bt = beta[oc] - stats[oc] * g;
        float4 v = ((const float4*)out)[i];
        float4 r;
        float y;
        y = v.x * g + bt; r.x = 0.5f * y * (1.f + erff(y * is2));
        y = v.y * g + bt; r.y = 0.5f * y * (1.f + erff(y * is2));
        y = v.z * g + bt; r.z = 0.5f * y * (1.f + erff(y * is2));
        y = v.w * g + bt; r.w = 0.5f * y * (1.f + erff(y * is2));
        ((float4*)out)[i] = r;
    }
}

// ---------------------------------------------------------------- launch
extern "C" void kernel_launch(void* const* d_in, const int* in_sizes, int n_in,
                              void* d_out, int out_size, void* d_ws, size_t ws_size,
                              hipStream_t stream) {
    const float* x      = (const float*)d_in[0];
    const float* proj_w = (const float*)d_in[1];
    // d_in[2] = proj_b: per-channel constant, cancels exactly in BatchNorm -> unused
    const float* off_w  = (const float*)d_in[3];
    const float* off_b  = (const float*)d_in[4];
    const float* mod_w  = (const float*)d_in[5];
    const float* mod_b  = (const float*)d_in[6];
    const float* gamma  = (const float*)d_in[7];
    const float* beta   = (const float*)d_in[8];
    float* ws  = (float*)d_ws;
    float* out = (float*)d_out;

    k_transpose  <<<dim3(128, 16, 8), dim3(32, 8), 0, stream>>>(x, ws + OFF_XT);
    k_prep_w     <<<dim3(512), dim3(256), 0, stream>>>(proj_w, off_w, mod_w, ws);
    k_conv27     <<<dim3(128, 4), dim3(256), 0, stream>>>(x, ws + OFF_W27T, ws + OFF_PARTIAL);
    k_deform_proj<<<dim3(512), dim3(256), 0, stream>>>(ws + OFF_XT, ws + OFF_PARTIAL,
                                                       off_b, mod_b, ws + OFF_PWT, out);
    k_bn_stats   <<<dim3(128), dim3(256), 0, stream>>>(out, ws + OFF_STATS);
    k_bn_gelu    <<<dim3(2048), dim3(256), 0, stream>>>(out, ws + OFF_STATS, gamma, beta);
}

// Round 4
// 1017.931 us; speedup vs baseline: 1.6091x; 1.6091x over previous
//
#include <hip/hip_runtime.h>
#include <hip/hip_bf16.h>
#include <math.h>

// Problem constants
#define BB   8
#define CIN  512
#define HH   64
#define WW   64
#define COUT 128
#define HW   4096        // HH*WW
#define PIX  32768       // BB*HW
#define MAXOFF 16.0f     // min(H,W)//4

// Workspace layout (float offsets)
#define OFF_XT      0ull            // x transposed NHWC: 8*4096*512        = 16,777,216
#define OFF_PARTIAL 16777216ull     // conv27 partials [4][8][27][4096]     =  3,538,944
#define OFF_IMG     20316160ull     // pre-swizzled bf16 proj_w LDS image   =    294,912 floats (1.18MB)
#define OFF_W27T    20611072ull     // off/mod w [c][tap][28] 512*252       =    129,024
#define OFF_STATS   20740096ull     // mean[128], rstd[128]
// total = 20,740,352 floats = 83.0 MB

typedef short bf16x8 __attribute__((ext_vector_type(8)));
typedef float f32x16 __attribute__((ext_vector_type(16)));

__device__ __forceinline__ unsigned short f2bf(float f) {
    unsigned int u = __builtin_bit_cast(unsigned int, f);
    u += 0x7FFFu + ((u >> 16) & 1u);          // RNE (finite inputs)
    return (unsigned short)(u >> 16);
}

// ---------------------------------------------------------------- transpose
// x [b][c][p] -> xt [b][p][c]   (p = h*64+w)
__global__ __launch_bounds__(256) void k_transpose(const float* __restrict__ x,
                                                   float* __restrict__ xt) {
    __shared__ float tile[32][33];
    int b  = blockIdx.z;
    int p0 = blockIdx.x * 32;
    int c0 = blockIdx.y * 32;
    int tx = threadIdx.x, ty = threadIdx.y;          // 32 x 8
    const float* src = x  + (size_t)b * CIN * HW;
    float*       dst = xt + (size_t)b * HW  * CIN;
    #pragma unroll
    for (int i = 0; i < 4; ++i)
        tile[ty + i*8][tx] = src[(size_t)(c0 + ty + i*8) * HW + p0 + tx];
    __syncthreads();
    #pragma unroll
    for (int i = 0; i < 4; ++i)
        dst[(size_t)(p0 + ty + i*8) * CIN + c0 + tx] = tile[tx][ty + i*8];
}

// ---------------------------------------------------------------- weight repack
// img: per (tap,ch-chunk) 16KB block that is the EXACT (XOR-swizzled) LDS image of
// w_tile[oc][c_local] bf16 — staged linearly at runtime (rule 21: pre-swizzled source).
// LDS halfword (oc*64 + j) must hold w[oc][ch*64 + (j ^ ((oc&7)<<3))].
__global__ void k_prep_w(const float* __restrict__ proj_w,
                         const float* __restrict__ off_w,
                         const float* __restrict__ mod_w,
                         float* __restrict__ ws) {
    unsigned int* img  = (unsigned int*)(ws + OFF_IMG);   // 294,912 u32 words
    float*        w27t = ws + OFF_W27T;                   // [c][tap][28]
    const int nimg  = 294912;
    const int total = nimg + 129024;
    for (int i = blockIdx.x * blockDim.x + threadIdx.x; i < total;
         i += gridDim.x * blockDim.x) {
        if (i < nimg) {
            int pos = i * 2;                // halfword position
            int blk = pos >> 13;            // 0..71  (tap*8 + chsub)
            int k   = blk >> 3;
            int chb = (blk & 7) << 6;
            int idx = pos & 8191;
            int oc  = idx >> 6;
            int j   = idx & 63;             // even
            int sw  = (oc & 7) << 3;
            int c0  = chb + (j ^ sw);
            int c1  = chb + ((j + 1) ^ sw);
            unsigned short lo = f2bf(proj_w[(size_t)(oc * 512 + c0) * 9 + k]);
            unsigned short hi = f2bf(proj_w[(size_t)(oc * 512 + c1) * 9 + k]);
            img[i] = (unsigned int)lo | ((unsigned int)hi << 16);
        } else {
            int j = i - nimg;               // index into [c][tap][28]
            int c = j / 252, r = j % 252;
            int tap = r / 28, oc = r % 28;
            float v = 0.f;
            if (oc < 18)      v = off_w[(size_t)oc * 4608 + c * 9 + tap];
            else if (oc < 27) v = mod_w[(size_t)(oc - 18) * 4608 + c * 9 + tap];
            w27t[c * 252 + tap * 28 + oc] = v;   // oc==27 -> 0 pad
        }
    }
}

// ---------------------------------------------------------------- offset/modulator conv
// thread = one pixel, computes all 27 output channels over a 128-channel c-slice.
// partial [csub][b][27][hw]
__global__ __launch_bounds__(256) void k_conv27(const float* __restrict__ x,
                                                const float* __restrict__ w27t,
                                                float* __restrict__ partial) {
    int tid  = threadIdx.x;
    int p    = blockIdx.x * 256 + tid;
    int csub = blockIdx.y;
    int b  = p >> 12;
    int hw = p & 4095;
    int h  = hw >> 6, w = hw & 63;

    float acc[28];
    #pragma unroll
    for (int i = 0; i < 28; ++i) acc[i] = 0.f;

    const float* xb = x + (size_t)b * CIN * HW;
    int c0 = csub * 128;
    for (int c = c0; c < c0 + 128; ++c) {
        float xv[9];
        #pragma unroll
        for (int t = 0; t < 9; ++t) {
            int yy = h + t / 3 - 1, xx = w + t % 3 - 1;
            bool v = (yy >= 0) && (yy < 64) && (xx >= 0) && (xx < 64);
            xv[t] = v ? xb[(size_t)c * HW + yy * 64 + xx] : 0.f;
        }
        const float4* wp = (const float4*)(w27t + c * 252); // uniform -> s_load
        #pragma unroll
        for (int t = 0; t < 9; ++t) {
            #pragma unroll
            for (int q = 0; q < 7; ++q) {
                float4 wv = wp[t * 7 + q];
                acc[q*4+0] += xv[t] * wv.x;
                acc[q*4+1] += xv[t] * wv.y;
                acc[q*4+2] += xv[t] * wv.z;
                acc[q*4+3] += xv[t] * wv.w;   // q==6,l==3 -> pad acc[27], never stored
            }
        }
    }
    float* dst = partial + ((size_t)(csub * 8 + b) * 27) * HW + hw;
    #pragma unroll
    for (int oc = 0; oc < 27; ++oc) dst[(size_t)oc * HW] = acc[oc];
}

// ---------------------------------------------------------------- fused deformable sample + projection (bf16 MFMA)
// Block = 512 thr (8 waves) = one (b, h-pair): 128 px x 128 oc output, K = 9 taps x 512 c.
// Per iter (tap k, 64-c chunk): gather A[128px][64c] bf16 (XOR-swizzled) + stage B
// weights [128oc][64c] bf16 (pre-swizzled image, linear copy), double-buffered;
// GEMM via mfma_f32_32x32x16_bf16 with A=weights (rows=oc), B=samples (cols=px)
// so D cols = px = lane&31 -> coalesced stores. proj_b omitted (cancels in BN).
__global__ __launch_bounds__(512) void k_deform_proj(const float* __restrict__ xt,
                                                     const float* __restrict__ partial,
                                                     const float* __restrict__ off_b,
                                                     const float* __restrict__ mod_b,
                                                     const unsigned short* __restrict__ img,
                                                     float* __restrict__ out) {
    __shared__ int    sy0[9][128];
    __shared__ int    sx0[9][128];
    __shared__ float4 sw4[9][128];
    __shared__ __align__(16) unsigned short sA[2][8192];   // samples [px][c] swizzled
    __shared__ __align__(16) unsigned short sB[2][8192];   // weights [oc][c] swizzled

    int tid  = threadIdx.x;
    int wid  = tid >> 6;
    int lane = tid & 63;
    int b    = blockIdx.x >> 5;
    int h0   = (blockIdx.x & 31) * 2;

    // ---- per-(pixel,tap) sampling params (all 9 taps, 128 px)
    for (int i = tid; i < 1152; i += 512) {
        int k = i >> 7, px = i & 127;
        int hw = (h0 + (px >> 6)) * 64 + (px & 63);
        float oy = off_b[2 * k], ox = off_b[2 * k + 1], om = mod_b[k];
        #pragma unroll
        for (int s = 0; s < 4; ++s) {
            const float* pp = partial + ((size_t)(s * 8 + b) * 27) * HW + hw;
            oy += pp[(size_t)(2 * k)     * HW];
            ox += pp[(size_t)(2 * k + 1) * HW];
            om += pp[(size_t)(18 + k)    * HW];
        }
        oy = fminf(fmaxf(oy, -MAXOFF), MAXOFF);
        ox = fminf(fmaxf(ox, -MAXOFF), MAXOFF);
        float m = 2.f / (1.f + expf(-om));
        float py  = (float)(h0 + (px >> 6)) + (float)(k / 3) - 1.f + oy;
        float pxf = (float)(px & 63)        + (float)(k % 3) - 1.f + ox;
        float y0f = floorf(py), x0f = floorf(pxf);
        float fy = py - y0f, fx = pxf - x0f;
        sy0[k][px] = (int)y0f;
        sx0[k][px] = (int)x0f;
        sw4[k][px] = make_float4((1.f - fy) * (1.f - fx) * m,
                                 (1.f - fy) * fx         * m,
                                 fy         * (1.f - fx) * m,
                                 fy         * fx         * m);
    }
    __syncthreads();

    f32x16 acc0 = {0,0,0,0,0,0,0,0,0,0,0,0,0,0,0,0};
    f32x16 acc1 = {0,0,0,0,0,0,0,0,0,0,0,0,0,0,0,0};

    const float* xtb0 = xt + (size_t)b * HW * CIN;
    int o  = wid & 3;                 // oc-tile (32 oc)
    int p0 = (wid >> 2) << 1;         // first of 2 px-tiles
    int swz   = (lane & 7) << 3;
    int khalf = (lane >> 5) << 3;

    // ---- prologue: stage iter 0 into buffer 0
    {
        const uint4* bsrc = (const uint4*)img;
        uint4* bdst = (uint4*)&sB[0][0];
        bdst[tid]       = bsrc[tid];
        bdst[tid + 512] = bsrc[tid + 512];
        const float* xtb = xtb0;
        #pragma unroll
        for (int pp = 0; pp < 16; ++pp) {
            int px = (wid << 4) + pp;
            int iy0 = sy0[0][px], ix0 = sx0[0][px];
            float4 wv = sw4[0][px];
            const float* r0 = xtb + (ptrdiff_t)(iy0 * 64 + ix0) * CIN + lane;
            float v00 = 0.f, v01 = 0.f, v10 = 0.f, v11 = 0.f;
            bool y0v = (unsigned)iy0 < 64u, y1v = (unsigned)(iy0 + 1) < 64u;
            bool x0v = (unsigned)ix0 < 64u, x1v = (unsigned)(ix0 + 1) < 64u;
            if (y0v && x0v) v00 = r0[0];
            if (y0v && x1v) v01 = r0[512];
            if (y1v && x0v) v10 = r0[32768];
            if (y1v && x1v) v11 = r0[33280];
            float sv = wv.x * v00 + wv.y * v01 + wv.z * v10 + wv.w * v11;
            sA[0][(px << 6) + (lane ^ ((px & 7) << 3))] = f2bf(sv);
        }
    }
    __syncthreads();

    int cur = 0;
    for (int it = 0; it < 72; ++it) {
        // stage next tile into cur^1 (loads issued before GEMM for overlap)
        if (it + 1 < 72) {
            int nb = cur ^ 1;
            int kT = (it + 1) >> 3;
            int ch = ((it + 1) & 7) << 6;
            const uint4* bsrc = (const uint4*)(img + (size_t)(it + 1) * 8192);
            uint4* bdst = (uint4*)&sB[nb][0];
            bdst[tid]       = bsrc[tid];
            bdst[tid + 512] = bsrc[tid + 512];
            const float* xtb = xtb0 + ch;
            #pragma unroll
            for (int pp = 0; pp < 16; ++pp) {
                int px = (wid << 4) + pp;
                int iy0 = sy0[kT][px], ix0 = sx0[kT][px];
                float4 wv = sw4[kT][px];
                const float* r0 = xtb + (ptrdiff_t)(iy0 * 64 + ix0) * CIN + lane;
                float v00 = 0.f, v01 = 0.f, v10 = 0.f, v11 = 0.f;
                bool y0v = (unsigned)iy0 < 64u, y1v = (unsigned)(iy0 + 1) < 64u;
                bool x0v = (unsigned)ix0 < 64u, x1v = (unsigned)(ix0 + 1) < 64u;
                if (y0v && x0v) v00 = r0[0];
                if (y0v && x1v) v01 = r0[512];
                if (y1v && x0v) v10 = r0[32768];
                if (y1v && x1v) v11 = r0[33280];
                float sv = wv.x * v00 + wv.y * v01 + wv.z * v10 + wv.w * v11;
                sA[nb][(px << 6) + (lane ^ ((px & 7) << 3))] = f2bf(sv);
            }
        }
        // GEMM on current buffer
        {
            const unsigned short* Wb = &sB[cur][((o << 5)  + (lane & 31)) << 6];
            const unsigned short* S0 = &sA[cur][((p0 << 5) + (lane & 31)) << 6];
            const unsigned short* S1 = S0 + (32 << 6);
            #pragma unroll
            for (int kk = 0; kk < 4; ++kk) {
                int ci = ((kk << 4) + khalf) ^ swz;
                bf16x8 wf = *(const bf16x8*)&Wb[ci];
                bf16x8 s0 = *(const bf16x8*)&S0[ci];
                bf16x8 s1 = *(const bf16x8*)&S1[ci];
                acc0 = __builtin_amdgcn_mfma_f32_32x32x16_bf16(wf, s0, acc0, 0, 0, 0);
                acc1 = __builtin_amdgcn_mfma_f32_32x32x16_bf16(wf, s1, acc1, 0, 0, 0);
            }
        }
        __syncthreads();
        cur ^= 1;
    }

    // ---- epilogue: D col = px = lane&31 -> coalesced 128B half-wave stores
    int oc_base = (o << 5) + ((lane >> 5) << 2);
    int px_base = (p0 << 5) + (lane & 31);
    float* ob = out + (size_t)b * COUT * HW;
    #pragma unroll
    for (int t = 0; t < 2; ++t) {
        int px = px_base + (t << 5);
        int hh = h0 + (px >> 6);
        int wc = px & 63;
        #pragma unroll
        for (int r = 0; r < 16; ++r) {
            int oc = oc_base + (r & 3) + ((r >> 2) << 3);
            float v = t ? acc1[r] : acc0[r];
            ob[((size_t)oc << 12) + (hh << 6) + wc] = v;
        }
    }
}

// ---------------------------------------------------------------- BN statistics (per channel)
__global__ __launch_bounds__(256) void k_bn_stats(const float* __restrict__ pre,
                                                  float* __restrict__ stats) {
    int oc  = blockIdx.x;
    int tid = threadIdx.x;
    float s = 0.f, ss = 0.f;
    for (int i = tid; i < PIX; i += 256) {
        int b = i >> 12, hw = i & 4095;
        float v = pre[((size_t)(b * COUT + oc)) * HW + hw];
        s += v; ss += v * v;
    }
    #pragma unroll
    for (int off = 32; off > 0; off >>= 1) {
        s  += __shfl_down(s,  off, 64);
        ss += __shfl_down(ss, off, 64);
    }
    __shared__ float red[8];
    int wid = tid >> 6, lane = tid & 63;
    if (lane == 0) { red[wid] = s; red[4 + wid] = ss; }
    __syncthreads();
    if (tid == 0) {
        float S  = red[0] + red[1] + red[2] + red[3];
        float SS = red[4] + red[5] + red[6] + red[7];
        float mean = S / (float)PIX;
        float var  = SS / (float)PIX - mean * mean;
        stats[oc]       = mean;
        stats[128 + oc] = rsqrtf(var + 1e-5f);
    }
}

// ---------------------------------------------------------------- BN apply + exact GELU (in-place on d_out)
__global__ __launch_bounds__(256) void k_bn_gelu(float* __restrict__ out,
                                                 const float* __restrict__ stats,
                                                 const float* __restrict__ gamma,
                                                 const float* __restrict__ beta) {
    const int n4 = (BB * COUT * HW) / 4;   // 1,048,576 float4
    const float is2 = 0.70710678118654752f;
    for (int i = blockIdx.x * blockDim.x + threadIdx.x; i < n4;
         i += gridDim.x * blockDim.x) {
        int oc = (i >> 10) & 127;          // 1024 float4 per (b,oc) plane
        float g  = gamma[oc] * stats[128 + oc];
        float bt = beta[oc] - stats[oc] * g;
        float4 v = ((const float4*)out)[i];
        float4 r;
        float y;
        y = v.x * g + bt; r.x = 0.5f * y * (1.f + erff(y * is2));
        y = v.y * g + bt; r.y = 0.5f * y * (1.f + erff(y * is2));
        y = v.z * g + bt; r.z = 0.5f * y * (1.f + erff(y * is2));
        y = v.w * g + bt; r.w = 0.5f * y * (1.f + erff(y * is2));
        ((float4*)out)[i] = r;
    }
}

// ---------------------------------------------------------------- launch
extern "C" void kernel_launch(void* const* d_in, const int* in_sizes, int n_in,
                              void* d_out, int out_size, void* d_ws, size_t ws_size,
                              hipStream_t stream) {
    const float* x      = (const float*)d_in[0];
    const float* proj_w = (const float*)d_in[1];
    // d_in[2] = proj_b: per-channel constant, cancels exactly in BatchNorm -> unused
    const float* off_w  = (const float*)d_in[3];
    const float* off_b  = (const float*)d_in[4];
    const float* mod_w  = (const float*)d_in[5];
    const float* mod_b  = (const float*)d_in[6];
    const float* gamma  = (const float*)d_in[7];
    const float* beta   = (const float*)d_in[8];
    float* ws  = (float*)d_ws;
    float* out = (float*)d_out;

    k_transpose  <<<dim3(128, 16, 8), dim3(32, 8), 0, stream>>>(x, ws + OFF_XT);
    k_prep_w     <<<dim3(512), dim3(256), 0, stream>>>(proj_w, off_w, mod_w, ws);
    k_conv27     <<<dim3(128, 4), dim3(256), 0, stream>>>(x, ws + OFF_W27T, ws + OFF_PARTIAL);
    k_deform_proj<<<dim3(256), dim3(512), 0, stream>>>(ws + OFF_XT, ws + OFF_PARTIAL,
                                                       off_b, mod_b,
                                                       (const unsigned short*)(ws + OFF_IMG), out);
    k_bn_stats   <<<dim3(128), dim3(256), 0, stream>>>(out, ws + OFF_STATS);
    k_bn_gelu    <<<dim3(2048), dim3(256), 0, stream>>>(out, ws + OFF_STATS, gamma, beta);
}

// Round 5
// 672.960 us; speedup vs baseline: 2.4339x; 1.5126x over previous
//
#include <hip/hip_runtime.h>
#include <hip/hip_bf16.h>
#include <hip/hip_fp16.h>
#include <math.h>

// Problem constants
#define BB   8
#define CIN  512
#define HH   64
#define WW   64
#define COUT 128
#define HW   4096        // HH*WW
#define PIX  32768       // BB*HW
#define MAXOFF 16.0f     // min(H,W)//4

// Workspace layout (float offsets)
#define OFF_XT      0ull            // x transposed NHWC: 8*4096*512        = 16,777,216
#define OFF_PARTIAL 16777216ull     // conv27 partials [4][8][27][4096]     =  3,538,944
#define OFF_IMG     20316160ull     // pre-swizzled bf16 proj_w LDS image   =    294,912 floats (1.18MB)
#define OFF_W27T    20611072ull     // off/mod w [c][tap][28] 512*252       =    129,024
#define OFF_STATS   20740096ull     // mean[128], rstd[128]
// total = 20,740,352 floats = 83.0 MB

typedef short bf16x8 __attribute__((ext_vector_type(8)));
typedef float f32x16 __attribute__((ext_vector_type(16)));

__device__ __forceinline__ unsigned short f2bf(float f) {
    unsigned int u = __builtin_bit_cast(unsigned int, f);
    u += 0x7FFFu + ((u >> 16) & 1u);          // RNE (finite inputs)
    return (unsigned short)(u >> 16);
}

// global -> LDS direct DMA, 16B per lane. LDS dest: wave-uniform base + lane*16.
#define GLL16(gsrc, ldst) \
    __builtin_amdgcn_global_load_lds((const __attribute__((address_space(1))) void*)(gsrc), \
                                     (__attribute__((address_space(3))) void*)(ldst), 16, 0, 0)

// ---------------------------------------------------------------- transpose
// x [b][c][p] -> xt [b][p][c]   (p = h*64+w)
__global__ __launch_bounds__(256) void k_transpose(const float* __restrict__ x,
                                                   float* __restrict__ xt) {
    __shared__ float tile[32][33];
    int b  = blockIdx.z;
    int p0 = blockIdx.x * 32;
    int c0 = blockIdx.y * 32;
    int tx = threadIdx.x, ty = threadIdx.y;          // 32 x 8
    const float* src = x  + (size_t)b * CIN * HW;
    float*       dst = xt + (size_t)b * HW  * CIN;
    #pragma unroll
    for (int i = 0; i < 4; ++i)
        tile[ty + i*8][tx] = src[(size_t)(c0 + ty + i*8) * HW + p0 + tx];
    __syncthreads();
    #pragma unroll
    for (int i = 0; i < 4; ++i)
        dst[(size_t)(p0 + ty + i*8) * CIN + c0 + tx] = tile[tx][ty + i*8];
}

// ---------------------------------------------------------------- weight repack
// img: per (tap,ch-chunk) 16KB block that is the EXACT (XOR-swizzled) LDS image of
// w_tile[oc][c_local] bf16 — staged linearly at runtime (rule 21: pre-swizzled source).
// LDS halfword (oc*64 + j) must hold w[oc][ch*64 + (j ^ ((oc&7)<<3))].
__global__ void k_prep_w(const float* __restrict__ proj_w,
                         const float* __restrict__ off_w,
                         const float* __restrict__ mod_w,
                         float* __restrict__ ws) {
    unsigned int* img  = (unsigned int*)(ws + OFF_IMG);   // 294,912 u32 words
    float*        w27t = ws + OFF_W27T;                   // [c][tap][28]
    const int nimg  = 294912;
    const int total = nimg + 129024;
    for (int i = blockIdx.x * blockDim.x + threadIdx.x; i < total;
         i += gridDim.x * blockDim.x) {
        if (i < nimg) {
            int pos = i * 2;                // halfword position
            int blk = pos >> 13;            // 0..71  (tap*8 + chsub)
            int k   = blk >> 3;
            int chb = (blk & 7) << 6;
            int idx = pos & 8191;
            int oc  = idx >> 6;
            int j   = idx & 63;             // even
            int sw  = (oc & 7) << 3;
            int c0  = chb + (j ^ sw);
            int c1  = chb + ((j + 1) ^ sw);
            unsigned short lo = f2bf(proj_w[(size_t)(oc * 512 + c0) * 9 + k]);
            unsigned short hi = f2bf(proj_w[(size_t)(oc * 512 + c1) * 9 + k]);
            img[i] = (unsigned int)lo | ((unsigned int)hi << 16);
        } else {
            int j = i - nimg;               // index into [c][tap][28]
            int c = j / 252, r = j % 252;
            int tap = r / 28, oc = r % 28;
            float v = 0.f;
            if (oc < 18)      v = off_w[(size_t)oc * 4608 + c * 9 + tap];
            else if (oc < 27) v = mod_w[(size_t)(oc - 18) * 4608 + c * 9 + tap];
            w27t[c * 252 + tap * 28 + oc] = v;   // oc==27 -> 0 pad
        }
    }
}

// ---------------------------------------------------------------- offset/modulator conv
// thread = one pixel, computes all 27 output channels over a 128-channel c-slice.
// partial [csub][b][27][hw]
__global__ __launch_bounds__(256) void k_conv27(const float* __restrict__ x,
                                                const float* __restrict__ w27t,
                                                float* __restrict__ partial) {
    int tid  = threadIdx.x;
    int p    = blockIdx.x * 256 + tid;
    int csub = blockIdx.y;
    int b  = p >> 12;
    int hw = p & 4095;
    int h  = hw >> 6, w = hw & 63;

    float acc[28];
    #pragma unroll
    for (int i = 0; i < 28; ++i) acc[i] = 0.f;

    const float* xb = x + (size_t)b * CIN * HW;
    int c0 = csub * 128;
    for (int c = c0; c < c0 + 128; ++c) {
        float xv[9];
        #pragma unroll
        for (int t = 0; t < 9; ++t) {
            int yy = h + t / 3 - 1, xx = w + t % 3 - 1;
            bool v = (yy >= 0) && (yy < 64) && (xx >= 0) && (xx < 64);
            xv[t] = v ? xb[(size_t)c * HW + yy * 64 + xx] : 0.f;
        }
        const float4* wp = (const float4*)(w27t + c * 252); // uniform -> s_load
        #pragma unroll
        for (int t = 0; t < 9; ++t) {
            #pragma unroll
            for (int q = 0; q < 7; ++q) {
                float4 wv = wp[t * 7 + q];
                acc[q*4+0] += xv[t] * wv.x;
                acc[q*4+1] += xv[t] * wv.y;
                acc[q*4+2] += xv[t] * wv.z;
                acc[q*4+3] += xv[t] * wv.w;   // q==6,l==3 -> pad acc[27], never stored
            }
        }
    }
    float* dst = partial + ((size_t)(csub * 8 + b) * 27) * HW + hw;
    #pragma unroll
    for (int oc = 0; oc < 27; ++oc) dst[(size_t)oc * HW] = acc[oc];
}

// ---------------------------------------------------------------- fused deformable sample + projection (bf16 MFMA)
// Block = 512 thr (8 waves) = one (b, h-pair): 128 px x 128 oc output, K = 9 taps x 512 c.
// Sampling params pre-clamped & validity-folded: positions packed 4x6 bits, weights
// 4x fp16 with OOB corners zeroed -> hot gather loop has 4 UNCONDITIONAL loads + 4 FMA.
// LDS = 79,360 B -> 2 blocks/CU (vs 93K/1 block before). B-tile staged via global_load_lds.
__global__ __launch_bounds__(512, 4) void k_deform_proj(const float* __restrict__ xt,
                                                        const float* __restrict__ partial,
                                                        const float* __restrict__ off_b,
                                                        const float* __restrict__ mod_b,
                                                        const unsigned short* __restrict__ img,
                                                        float* __restrict__ out) {
    __shared__ unsigned int spos[9][128];                  // y0c|y1c<<6|x0c<<12|x1c<<18
    __shared__ uint2        swh [9][128];                  // 4 x fp16 validity-folded weights
    __shared__ __align__(16) unsigned short sA[2][8192];   // samples [px][c] swizzled
    __shared__ __align__(16) unsigned short sB[2][8192];   // weights [oc][c] swizzled

    int tid  = threadIdx.x;
    int wid  = tid >> 6;
    int lane = tid & 63;
    int b    = blockIdx.x >> 5;
    int h0   = (blockIdx.x & 31) * 2;

    // ---- per-(pixel,tap) sampling params (all 9 taps, 128 px)
    for (int i = tid; i < 1152; i += 512) {
        int k = i >> 7, px = i & 127;
        int hw = (h0 + (px >> 6)) * 64 + (px & 63);
        float oy = off_b[2 * k], ox = off_b[2 * k + 1], om = mod_b[k];
        #pragma unroll
        for (int s = 0; s < 4; ++s) {
            const float* pp = partial + ((size_t)(s * 8 + b) * 27) * HW + hw;
            oy += pp[(size_t)(2 * k)     * HW];
            ox += pp[(size_t)(2 * k + 1) * HW];
            om += pp[(size_t)(18 + k)    * HW];
        }
        oy = fminf(fmaxf(oy, -MAXOFF), MAXOFF);
        ox = fminf(fmaxf(ox, -MAXOFF), MAXOFF);
        float m = 2.f / (1.f + expf(-om));
        float py  = (float)(h0 + (px >> 6)) + (float)(k / 3) - 1.f + oy;
        float pxf = (float)(px & 63)        + (float)(k % 3) - 1.f + ox;
        float y0f = floorf(py), x0f = floorf(pxf);
        float fy = py - y0f, fx = pxf - x0f;
        int iy0 = (int)y0f, ix0 = (int)x0f;
        bool y0v = (unsigned)iy0 < 64u, y1v = (unsigned)(iy0 + 1) < 64u;
        bool x0v = (unsigned)ix0 < 64u, x1v = (unsigned)(ix0 + 1) < 64u;
        int y0c = min(max(iy0, 0), 63),     y1c = min(max(iy0 + 1, 0), 63);
        int x0c = min(max(ix0, 0), 63),     x1c = min(max(ix0 + 1, 0), 63);
        float w00 = (1.f - fy) * (1.f - fx) * m * (float)(y0v && x0v);
        float w01 = (1.f - fy) * fx         * m * (float)(y0v && x1v);
        float w10 = fy         * (1.f - fx) * m * (float)(y1v && x0v);
        float w11 = fy         * fx         * m * (float)(y1v && x1v);
        spos[k][px] = (unsigned)y0c | ((unsigned)y1c << 6)
                    | ((unsigned)x0c << 12) | ((unsigned)x1c << 18);
        swh[k][px] = make_uint2(
            __builtin_bit_cast(unsigned int, __floats2half2_rn(w00, w01)),
            __builtin_bit_cast(unsigned int, __floats2half2_rn(w10, w11)));
    }
    __syncthreads();

    f32x16 acc0 = {0,0,0,0,0,0,0,0,0,0,0,0,0,0,0,0};
    f32x16 acc1 = {0,0,0,0,0,0,0,0,0,0,0,0,0,0,0,0};

    const float* xtb0 = xt + (size_t)b * HW * CIN;
    int o  = wid & 3;                 // oc-tile (32 oc)
    int p0 = (wid >> 2) << 1;         // first of 2 px-tiles
    int swz   = (lane & 7) << 3;
    int khalf = (lane >> 5) << 3;

    // ---- prologue: stage iter 0 into buffer 0
    {
        const uint4* bsrc = (const uint4*)img;
        uint4* ldsb = (uint4*)&sB[0][0];
        GLL16(bsrc + tid,       ldsb + (wid << 6));
        GLL16(bsrc + 512 + tid, ldsb + 512 + (wid << 6));
        const float* xtb = xtb0;
        #pragma unroll
        for (int pp = 0; pp < 16; ++pp) {
            int px = (wid << 4) + pp;
            unsigned pk = spos[0][px];
            uint2 wp = swh[0][px];
            float2 fA = __half22float2(__builtin_bit_cast(__half2, wp.x));
            float2 fB = __half22float2(__builtin_bit_cast(__half2, wp.y));
            int y0r = (pk & 63) << 6, y1r = ((pk >> 6) & 63) << 6;
            int x0c = (pk >> 12) & 63, x1c = (pk >> 18) & 63;
            float v00 = xtb[((y0r + x0c) << 9) + lane];
            float v01 = xtb[((y0r + x1c) << 9) + lane];
            float v10 = xtb[((y1r + x0c) << 9) + lane];
            float v11 = xtb[((y1r + x1c) << 9) + lane];
            float sv = fA.x * v00 + fA.y * v01 + fB.x * v10 + fB.y * v11;
            sA[0][(px << 6) + (lane ^ ((px & 7) << 3))] = f2bf(sv);
        }
    }
    __syncthreads();

    int cur = 0;
    for (int it = 0; it < 72; ++it) {
        // stage next tile into cur^1 (loads issued before GEMM for overlap)
        if (it + 1 < 72) {
            int nb = cur ^ 1;
            int kT = (it + 1) >> 3;
            int ch = ((it + 1) & 7) << 6;
            const uint4* bsrc = (const uint4*)(img + (size_t)(it + 1) * 8192);
            uint4* ldsb = (uint4*)&sB[nb][0];
            GLL16(bsrc + tid,       ldsb + (wid << 6));
            GLL16(bsrc + 512 + tid, ldsb + 512 + (wid << 6));
            const float* xtb = xtb0 + ch;
            #pragma unroll
            for (int pp = 0; pp < 16; ++pp) {
                int px = (wid << 4) + pp;
                unsigned pk = spos[kT][px];
                uint2 wp = swh[kT][px];
                float2 fA = __half22float2(__builtin_bit_cast(__half2, wp.x));
                float2 fB = __half22float2(__builtin_bit_cast(__half2, wp.y));
                int y0r = (pk & 63) << 6, y1r = ((pk >> 6) & 63) << 6;
                int x0c = (pk >> 12) & 63, x1c = (pk >> 18) & 63;
                float v00 = xtb[((y0r + x0c) << 9) + lane];
                float v01 = xtb[((y0r + x1c) << 9) + lane];
                float v10 = xtb[((y1r + x0c) << 9) + lane];
                float v11 = xtb[((y1r + x1c) << 9) + lane];
                float sv = fA.x * v00 + fA.y * v01 + fB.x * v10 + fB.y * v11;
                sA[nb][(px << 6) + (lane ^ ((px & 7) << 3))] = f2bf(sv);
            }
        }
        // GEMM on current buffer
        {
            const unsigned short* Wb = &sB[cur][((o << 5)  + (lane & 31)) << 6];
            const unsigned short* S0 = &sA[cur][((p0 << 5) + (lane & 31)) << 6];
            const unsigned short* S1 = S0 + (32 << 6);
            #pragma unroll
            for (int kk = 0; kk < 4; ++kk) {
                int ci = ((kk << 4) + khalf) ^ swz;
                bf16x8 wf = *(const bf16x8*)&Wb[ci];
                bf16x8 s0 = *(const bf16x8*)&S0[ci];
                bf16x8 s1 = *(const bf16x8*)&S1[ci];
                acc0 = __builtin_amdgcn_mfma_f32_32x32x16_bf16(wf, s0, acc0, 0, 0, 0);
                acc1 = __builtin_amdgcn_mfma_f32_32x32x16_bf16(wf, s1, acc1, 0, 0, 0);
            }
        }
        __syncthreads();
        cur ^= 1;
    }

    // ---- epilogue: D col = px = lane&31 -> coalesced 128B half-wave stores
    int oc_base = (o << 5) + ((lane >> 5) << 2);
    int px_base = (p0 << 5) + (lane & 31);
    float* ob = out + (size_t)b * COUT * HW;
    #pragma unroll
    for (int t = 0; t < 2; ++t) {
        int px = px_base + (t << 5);
        int hh = h0 + (px >> 6);
        int wc = px & 63;
        #pragma unroll
        for (int r = 0; r < 16; ++r) {
            int oc = oc_base + (r & 3) + ((r >> 2) << 3);
            float v = t ? acc1[r] : acc0[r];
            ob[((size_t)oc << 12) + (hh << 6) + wc] = v;
        }
    }
}

// ---------------------------------------------------------------- BN statistics (per channel)
__global__ __launch_bounds__(256) void k_bn_stats(const float* __restrict__ pre,
                                                  float* __restrict__ stats) {
    int oc  = blockIdx.x;
    int tid = threadIdx.x;
    float s = 0.f, ss = 0.f;
    for (int i = tid; i < PIX; i += 256) {
        int b = i >> 12, hw = i & 4095;
        float v = pre[((size_t)(b * COUT + oc)) * HW + hw];
        s += v; ss += v * v;
    }
    #pragma unroll
    for (int off = 32; off > 0; off >>= 1) {
        s  += __shfl_down(s,  off, 64);
        ss += __shfl_down(ss, off, 64);
    }
    __shared__ float red[8];
    int wid = tid >> 6, lane = tid & 63;
    if (lane == 0) { red[wid] = s; red[4 + wid] = ss; }
    __syncthreads();
    if (tid == 0) {
        float S  = red[0] + red[1] + red[2] + red[3];
        float SS = red[4] + red[5] + red[6] + red[7];
        float mean = S / (float)PIX;
        float var  = SS / (float)PIX - mean * mean;
        stats[oc]       = mean;
        stats[128 + oc] = rsqrtf(var + 1e-5f);
    }
}

// ---------------------------------------------------------------- BN apply + exact GELU (in-place on d_out)
__global__ __launch_bounds__(256) void k_bn_gelu(float* __restrict__ out,
                                                 const float* __restrict__ stats,
                                                 const float* __restrict__ gamma,
                                                 const float* __restrict__ beta) {
    const int n4 = (BB * COUT * HW) / 4;   // 1,048,576 float4
    const float is2 = 0.70710678118654752f;
    for (int i = blockIdx.x * blockDim.x + threadIdx.x; i < n4;
         i += gridDim.x * blockDim.x) {
        int oc = (i >> 10) & 127;          // 1024 float4 per (b,oc) plane
        float g  = gamma[oc] * stats[128 + oc];
        float bt = beta[oc] - stats[oc] * g;
        float4 v = ((const float4*)out)[i];
        float4 r;
        float y;
        y = v.x * g + bt; r.x = 0.5f * y * (1.f + erff(y * is2));
        y = v.y * g + bt; r.y = 0.5f * y * (1.f + erff(y * is2));
        y = v.z * g + bt; r.z = 0.5f * y * (1.f + erff(y * is2));
        y = v.w * g + bt; r.w = 0.5f * y * (1.f + erff(y * is2));
        ((float4*)out)[i] = r;
    }
}

// ---------------------------------------------------------------- launch
extern "C" void kernel_launch(void* const* d_in, const int* in_sizes, int n_in,
                              void* d_out, int out_size, void* d_ws, size_t ws_size,
                              hipStream_t stream) {
    const float* x      = (const float*)d_in[0];
    const float* proj_w = (const float*)d_in[1];
    // d_in[2] = proj_b: per-channel constant, cancels exactly in BatchNorm -> unused
    const float* off_w  = (const float*)d_in[3];
    const float* off_b  = (const float*)d_in[4];
    const float* mod_w  = (const float*)d_in[5];
    const float* mod_b  = (const float*)d_in[6];
    const float* gamma  = (const float*)d_in[7];
    const float* beta   = (const float*)d_in[8];
    float* ws  = (float*)d_ws;
    float* out = (float*)d_out;

    k_transpose  <<<dim3(128, 16, 8), dim3(32, 8), 0, stream>>>(x, ws + OFF_XT);
    k_prep_w     <<<dim3(512), dim3(256), 0, stream>>>(proj_w, off_w, mod_w, ws);
    k_conv27     <<<dim3(128, 4), dim3(256), 0, stream>>>(x, ws + OFF_W27T, ws + OFF_PARTIAL);
    k_deform_proj<<<dim3(256), dim3(512), 0, stream>>>(ws + OFF_XT, ws + OFF_PARTIAL,
                                                       off_b, mod_b,
                                                       (const unsigned short*)(ws + OFF_IMG), out);
    k_bn_stats   <<<dim3(128), dim3(256), 0, stream>>>(out, ws + OFF_STATS);
    k_bn_gelu    <<<dim3(2048), dim3(256), 0, stream>>>(out, ws + OFF_STATS, gamma, beta);
}

// Round 6
// 443.004 us; speedup vs baseline: 3.6974x; 1.5191x over previous
//
#include <hip/hip_runtime.h>
#include <hip/hip_bf16.h>
#include <hip/hip_fp16.h>
#include <math.h>

// Problem constants
#define BB   8
#define CIN  512
#define HH   64
#define WW   64
#define COUT 128
#define HW   4096        // HH*WW
#define PIX  32768       // BB*HW
#define MAXOFF 16.0f     // min(H,W)//4

// Workspace layout (float offsets)
#define OFF_XT      0ull            // x transposed NHWC: 8*4096*512        = 16,777,216
#define OFF_PARTIAL 16777216ull     // conv27 output [8][27][4096]          =    884,736
#define OFF_IMG     17661952ull     // pre-swizzled bf16 proj_w LDS image   =    294,912
#define OFF_A27     17956864ull     // pre-swizzled bf16 off/mod-w image    =     73,728
#define OFF_STATS   18030592ull     // mean[128], rstd[128]
// total = 18,030,848 floats = 72.1 MB

typedef short bf16x8 __attribute__((ext_vector_type(8)));
typedef unsigned short u16x8 __attribute__((ext_vector_type(8)));
typedef float f32x4  __attribute__((ext_vector_type(4)));
typedef float f32x16 __attribute__((ext_vector_type(16)));

__device__ __forceinline__ unsigned short f2bf(float f) {
    unsigned int u = __builtin_bit_cast(unsigned int, f);
    u += 0x7FFFu + ((u >> 16) & 1u);          // RNE (finite inputs)
    return (unsigned short)(u >> 16);
}

// global -> LDS direct DMA, 16B per lane. LDS dest: wave-uniform base + lane*16.
#define GLL16(gsrc, ldst) \
    __builtin_amdgcn_global_load_lds((const __attribute__((address_space(1))) void*)(gsrc), \
                                     (__attribute__((address_space(3))) void*)(ldst), 16, 0, 0)

// ---------------------------------------------------------------- transpose
// x [b][c][p] -> xt [b][p][c]   (p = h*64+w)
__global__ __launch_bounds__(256) void k_transpose(const float* __restrict__ x,
                                                   float* __restrict__ xt) {
    __shared__ float tile[32][33];
    int b  = blockIdx.z;
    int p0 = blockIdx.x * 32;
    int c0 = blockIdx.y * 32;
    int tx = threadIdx.x, ty = threadIdx.y;          // 32 x 8
    const float* src = x  + (size_t)b * CIN * HW;
    float*       dst = xt + (size_t)b * HW  * CIN;
    #pragma unroll
    for (int i = 0; i < 4; ++i)
        tile[ty + i*8][tx] = src[(size_t)(c0 + ty + i*8) * HW + p0 + tx];
    __syncthreads();
    #pragma unroll
    for (int i = 0; i < 4; ++i)
        dst[(size_t)(p0 + ty + i*8) * CIN + c0 + tx] = tile[tx][ty + i*8];
}

// ---------------------------------------------------------------- weight repack
// img: 72 blocks (tap*8+chsub) of [128 oc][64 c] bf16, XOR-swizzled LDS image of proj_w.
// a27: 72 blocks of [32 oc][64 c] bf16 (27 real + 5 zero rows), same swizzle, for conv27mm.
__global__ void k_prep_w(const float* __restrict__ proj_w,
                         const float* __restrict__ off_w,
                         const float* __restrict__ mod_w,
                         float* __restrict__ ws) {
    unsigned int* img = (unsigned int*)(ws + OFF_IMG);   // 294,912 u32 words
    unsigned int* a27 = (unsigned int*)(ws + OFF_A27);   //  73,728 u32 words
    const int nimg  = 294912;
    const int total = nimg + 73728;
    for (int i = blockIdx.x * blockDim.x + threadIdx.x; i < total;
         i += gridDim.x * blockDim.x) {
        if (i < nimg) {
            int pos = i * 2;                // halfword position
            int blk = pos >> 13;            // 0..71  (tap*8 + chsub)
            int k   = blk >> 3;
            int chb = (blk & 7) << 6;
            int idx = pos & 8191;
            int oc  = idx >> 6;
            int j   = idx & 63;             // even
            int sw  = (oc & 7) << 3;
            int c0  = chb + (j ^ sw);
            int c1  = chb + ((j + 1) ^ sw);
            unsigned short lo = f2bf(proj_w[(size_t)(oc * 512 + c0) * 9 + k]);
            unsigned short hi = f2bf(proj_w[(size_t)(oc * 512 + c1) * 9 + k]);
            img[i] = (unsigned int)lo | ((unsigned int)hi << 16);
        } else {
            int pos = (i - nimg) * 2;       // halfword into [72][32][64]
            int blk = pos >> 11;            // 0..71
            int k   = blk >> 3;
            int chb = (blk & 7) << 6;
            int idx = pos & 2047;
            int oc  = idx >> 6;             // 0..31
            int j   = idx & 63;             // even
            int sw  = (oc & 7) << 3;
            int c0  = chb + (j ^ sw);
            int c1  = chb + ((j + 1) ^ sw);
            float v0 = 0.f, v1 = 0.f;
            if (oc < 18)      { v0 = off_w[(size_t)(oc * 512 + c0) * 9 + k];
                                v1 = off_w[(size_t)(oc * 512 + c1) * 9 + k]; }
            else if (oc < 27) { v0 = mod_w[(size_t)((oc - 18) * 512 + c0) * 9 + k];
                                v1 = mod_w[(size_t)((oc - 18) * 512 + c1) * 9 + k]; }
            a27[i - nimg] = (unsigned int)f2bf(v0) | ((unsigned int)f2bf(v1) << 16);
        }
    }
}

// ---------------------------------------------------------------- offset/modulator conv as bf16 MFMA GEMM
// Block = (b,h) row, 512 thr (8 waves): D[32 oc][64 px], K = 9 taps x 512 c (72 iters of 64).
// B-tile [64px][64c] gathered from xt with static tap shifts; A-tile from pre-swizzled a27
// image via global_load_lds. Double-buffered, one barrier/iter. Writes [8][27][4096].
__global__ __launch_bounds__(512) void k_conv27mm(const float* __restrict__ xt,
                                                  const unsigned short* __restrict__ a27,
                                                  float* __restrict__ partial) {
    __shared__ __align__(16) unsigned short sB2[2][4096];   // [px][c] swizzled, 8 KB each
    __shared__ __align__(16) unsigned short sA2[2][2048];   // [oc][c] swizzled, 4 KB each

    int tid  = threadIdx.x;
    int wid  = tid >> 6;
    int lane = tid & 63;
    int b    = blockIdx.x >> 6;
    int h    = blockIdx.x & 63;

    const float* xtb0  = xt + (size_t)b * HW * CIN;
    const uint4* a27u4 = (const uint4*)a27;

    int px = tid >> 3;                 // staging pixel 0..63
    int cl = (tid & 7) << 3;           // staging c-chunk base (8 c)
    int sdst = (px << 6) + (cl ^ ((px & 7) << 3));   // swizzled halfword offset

    f32x4 acc = {0.f, 0.f, 0.f, 0.f};

    // ---- prologue: stage iter 0 into buffer 0
    {
        if (wid < 4) GLL16(a27u4 + tid, (uint4*)&sA2[0][0] + (wid << 6));
        // tap 0: kh=0, kw=0 -> row=h-1, col=px-1
        int row = h - 1, col = px - 1;
        float4 f0 = {0,0,0,0}, f1 = {0,0,0,0};
        if (((unsigned)row < 64u) && ((unsigned)col < 64u)) {
            const float* src = xtb0 + ((size_t)(row * 64 + col) << 9) + cl;
            f0 = *(const float4*)src;
            f1 = *(const float4*)(src + 4);
        }
        u16x8 u;
        u[0] = f2bf(f0.x); u[1] = f2bf(f0.y); u[2] = f2bf(f0.z); u[3] = f2bf(f0.w);
        u[4] = f2bf(f1.x); u[5] = f2bf(f1.y); u[6] = f2bf(f1.z); u[7] = f2bf(f1.w);
        *(u16x8*)&sB2[0][sdst] = u;
    }
    __syncthreads();

    int m = wid & 1, n = wid >> 1;
    int oc_f = (m << 4) + (lane & 15);
    int px_f = (n << 4) + (lane & 15);
    int kq   = (lane >> 4) << 3;
    int swA  = (oc_f & 7) << 3;
    int swB  = (px_f & 7) << 3;

    int cur = 0;
    for (int it = 0; it < 72; ++it) {
        if (it + 1 < 72) {
            int nb  = cur ^ 1;
            int it1 = it + 1;
            int tap = it1 >> 3;
            int chb = (it1 & 7) << 6;
            int kh = tap / 3, kw = tap - kh * 3;
            if (wid < 4) GLL16(a27u4 + (size_t)it1 * 256 + tid, (uint4*)&sA2[nb][0] + (wid << 6));
            int row = h + kh - 1, col = px + kw - 1;
            float4 f0 = {0,0,0,0}, f1 = {0,0,0,0};
            if (((unsigned)row < 64u) && ((unsigned)col < 64u)) {
                const float* src = xtb0 + ((size_t)(row * 64 + col) << 9) + chb + cl;
                f0 = *(const float4*)src;
                f1 = *(const float4*)(src + 4);
            }
            u16x8 u;
            u[0] = f2bf(f0.x); u[1] = f2bf(f0.y); u[2] = f2bf(f0.z); u[3] = f2bf(f0.w);
            u[4] = f2bf(f1.x); u[5] = f2bf(f1.y); u[6] = f2bf(f1.z); u[7] = f2bf(f1.w);
            *(u16x8*)&sB2[nb][sdst] = u;
        }
        // GEMM on current buffer: one 16x16 tile per wave, K=64 (2 MFMA)
        {
            const unsigned short* Arow = &sA2[cur][oc_f << 6];
            const unsigned short* Brow = &sB2[cur][px_f << 6];
            #pragma unroll
            for (int kk = 0; kk < 2; ++kk) {
                int ci = (kk << 5) + kq;
                bf16x8 af = *(const bf16x8*)&Arow[ci ^ swA];
                bf16x8 bf = *(const bf16x8*)&Brow[ci ^ swB];
                acc = __builtin_amdgcn_mfma_f32_16x16x32_bf16(af, bf, acc, 0, 0, 0);
            }
        }
        __syncthreads();
        cur ^= 1;
    }

    // ---- epilogue: D col=lane&15 (px), row=(lane>>4)*4+r (oc); store oc<27
    int rowbase = (lane >> 4) << 2;
    #pragma unroll
    for (int r = 0; r < 4; ++r) {
        int oc = (m << 4) + rowbase + r;
        if (oc < 27)
            partial[((size_t)(b * 27 + oc) << 12) + (h << 6) + (n << 4) + (lane & 15)] = acc[r];
    }
}

// ---------------------------------------------------------------- fused deformable sample + projection (bf16 MFMA)
// Block = 512 thr (8 waves) = one (b, h-pair): 128 px x 128 oc output, K = 9 taps x 512 c.
// Sampling params pre-clamped & validity-folded: positions packed 4x6 bits, weights
// 4x fp16 with OOB corners zeroed -> hot gather loop has 4 UNCONDITIONAL loads + 4 FMA.
// LDS = 79,360 B -> 2 blocks/CU. B-tile staged via global_load_lds.
__global__ __launch_bounds__(512, 4) void k_deform_proj(const float* __restrict__ xt,
                                                        const float* __restrict__ partial,
                                                        const float* __restrict__ off_b,
                                                        const float* __restrict__ mod_b,
                                                        const unsigned short* __restrict__ img,
                                                        float* __restrict__ out) {
    __shared__ unsigned int spos[9][128];                  // y0c|y1c<<6|x0c<<12|x1c<<18
    __shared__ uint2        swh [9][128];                  // 4 x fp16 validity-folded weights
    __shared__ __align__(16) unsigned short sA[2][8192];   // samples [px][c] swizzled
    __shared__ __align__(16) unsigned short sB[2][8192];   // weights [oc][c] swizzled

    int tid  = threadIdx.x;
    int wid  = tid >> 6;
    int lane = tid & 63;
    int b    = blockIdx.x >> 5;
    int h0   = (blockIdx.x & 31) * 2;

    // ---- per-(pixel,tap) sampling params (all 9 taps, 128 px)
    for (int i = tid; i < 1152; i += 512) {
        int k = i >> 7, px = i & 127;
        int hw = (h0 + (px >> 6)) * 64 + (px & 63);
        const float* pp = partial + (size_t)(b * 27) * HW + hw;
        float oy = off_b[2 * k]     + pp[(size_t)(2 * k)     * HW];
        float ox = off_b[2 * k + 1] + pp[(size_t)(2 * k + 1) * HW];
        float om = mod_b[k]         + pp[(size_t)(18 + k)    * HW];
        oy = fminf(fmaxf(oy, -MAXOFF), MAXOFF);
        ox = fminf(fmaxf(ox, -MAXOFF), MAXOFF);
        float m = 2.f / (1.f + expf(-om));
        float py  = (float)(h0 + (px >> 6)) + (float)(k / 3) - 1.f + oy;
        float pxf = (float)(px & 63)        + (float)(k % 3) - 1.f + ox;
        float y0f = floorf(py), x0f = floorf(pxf);
        float fy = py - y0f, fx = pxf - x0f;
        int iy0 = (int)y0f, ix0 = (int)x0f;
        bool y0v = (unsigned)iy0 < 64u, y1v = (unsigned)(iy0 + 1) < 64u;
        bool x0v = (unsigned)ix0 < 64u, x1v = (unsigned)(ix0 + 1) < 64u;
        int y0c = min(max(iy0, 0), 63),     y1c = min(max(iy0 + 1, 0), 63);
        int x0c = min(max(ix0, 0), 63),     x1c = min(max(ix0 + 1, 0), 63);
        float w00 = (1.f - fy) * (1.f - fx) * m * (float)(y0v && x0v);
        float w01 = (1.f - fy) * fx         * m * (float)(y0v && x1v);
        float w10 = fy         * (1.f - fx) * m * (float)(y1v && x0v);
        float w11 = fy         * fx         * m * (float)(y1v && x1v);
        spos[k][px] = (unsigned)y0c | ((unsigned)y1c << 6)
                    | ((unsigned)x0c << 12) | ((unsigned)x1c << 18);
        swh[k][px] = make_uint2(
            __builtin_bit_cast(unsigned int, __floats2half2_rn(w00, w01)),
            __builtin_bit_cast(unsigned int, __floats2half2_rn(w10, w11)));
    }
    __syncthreads();

    f32x16 acc0 = {0,0,0,0,0,0,0,0,0,0,0,0,0,0,0,0};
    f32x16 acc1 = {0,0,0,0,0,0,0,0,0,0,0,0,0,0,0,0};

    const float* xtb0 = xt + (size_t)b * HW * CIN;
    int o  = wid & 3;                 // oc-tile (32 oc)
    int p0 = (wid >> 2) << 1;         // first of 2 px-tiles
    int swz   = (lane & 7) << 3;
    int khalf = (lane >> 5) << 3;

    // ---- prologue: stage iter 0 into buffer 0
    {
        const uint4* bsrc = (const uint4*)img;
        uint4* ldsb = (uint4*)&sB[0][0];
        GLL16(bsrc + tid,       ldsb + (wid << 6));
        GLL16(bsrc + 512 + tid, ldsb + 512 + (wid << 6));
        const float* xtb = xtb0;
        #pragma unroll
        for (int pp = 0; pp < 16; ++pp) {
            int px = (wid << 4) + pp;
            unsigned pk = spos[0][px];
            uint2 wp = swh[0][px];
            float2 fA = __half22float2(__builtin_bit_cast(__half2, wp.x));
            float2 fB = __half22float2(__builtin_bit_cast(__half2, wp.y));
            int y0r = (pk & 63) << 6, y1r = ((pk >> 6) & 63) << 6;
            int x0c = (pk >> 12) & 63, x1c = (pk >> 18) & 63;
            float v00 = xtb[((y0r + x0c) << 9) + lane];
            float v01 = xtb[((y0r + x1c) << 9) + lane];
            float v10 = xtb[((y1r + x0c) << 9) + lane];
            float v11 = xtb[((y1r + x1c) << 9) + lane];
            float sv = fA.x * v00 + fA.y * v01 + fB.x * v10 + fB.y * v11;
            sA[0][(px << 6) + (lane ^ ((px & 7) << 3))] = f2bf(sv);
        }
    }
    __syncthreads();

    int cur = 0;
    for (int it = 0; it < 72; ++it) {
        // stage next tile into cur^1 (loads issued before GEMM for overlap)
        if (it + 1 < 72) {
            int nb = cur ^ 1;
            int kT = (it + 1) >> 3;
            int ch = ((it + 1) & 7) << 6;
            const uint4* bsrc = (const uint4*)(img + (size_t)(it + 1) * 8192);
            uint4* ldsb = (uint4*)&sB[nb][0];
            GLL16(bsrc + tid,       ldsb + (wid << 6));
            GLL16(bsrc + 512 + tid, ldsb + 512 + (wid << 6));
            const float* xtb = xtb0 + ch;
            #pragma unroll
            for (int pp = 0; pp < 16; ++pp) {
                int px = (wid << 4) + pp;
                unsigned pk = spos[kT][px];
                uint2 wp = swh[kT][px];
                float2 fA = __half22float2(__builtin_bit_cast(__half2, wp.x));
                float2 fB = __half22float2(__builtin_bit_cast(__half2, wp.y));
                int y0r = (pk & 63) << 6, y1r = ((pk >> 6) & 63) << 6;
                int x0c = (pk >> 12) & 63, x1c = (pk >> 18) & 63;
                float v00 = xtb[((y0r + x0c) << 9) + lane];
                float v01 = xtb[((y0r + x1c) << 9) + lane];
                float v10 = xtb[((y1r + x0c) << 9) + lane];
                float v11 = xtb[((y1r + x1c) << 9) + lane];
                float sv = fA.x * v00 + fA.y * v01 + fB.x * v10 + fB.y * v11;
                sA[nb][(px << 6) + (lane ^ ((px & 7) << 3))] = f2bf(sv);
            }
        }
        // GEMM on current buffer
        {
            const unsigned short* Wb = &sB[cur][((o << 5)  + (lane & 31)) << 6];
            const unsigned short* S0 = &sA[cur][((p0 << 5) + (lane & 31)) << 6];
            const unsigned short* S1 = S0 + (32 << 6);
            #pragma unroll
            for (int kk = 0; kk < 4; ++kk) {
                int ci = ((kk << 4) + khalf) ^ swz;
                bf16x8 wf = *(const bf16x8*)&Wb[ci];
                bf16x8 s0 = *(const bf16x8*)&S0[ci];
                bf16x8 s1 = *(const bf16x8*)&S1[ci];
                acc0 = __builtin_amdgcn_mfma_f32_32x32x16_bf16(wf, s0, acc0, 0, 0, 0);
                acc1 = __builtin_amdgcn_mfma_f32_32x32x16_bf16(wf, s1, acc1, 0, 0, 0);
            }
        }
        __syncthreads();
        cur ^= 1;
    }

    // ---- epilogue: D col = px = lane&31 -> coalesced 128B half-wave stores
    int oc_base = (o << 5) + ((lane >> 5) << 2);
    int px_base = (p0 << 5) + (lane & 31);
    float* ob = out + (size_t)b * COUT * HW;
    #pragma unroll
    for (int t = 0; t < 2; ++t) {
        int px = px_base + (t << 5);
        int hh = h0 + (px >> 6);
        int wc = px & 63;
        #pragma unroll
        for (int r = 0; r < 16; ++r) {
            int oc = oc_base + (r & 3) + ((r >> 2) << 3);
            float v = t ? acc1[r] : acc0[r];
            ob[((size_t)oc << 12) + (hh << 6) + wc] = v;
        }
    }
}

// ---------------------------------------------------------------- BN statistics (per channel)
__global__ __launch_bounds__(256) void k_bn_stats(const float* __restrict__ pre,
                                                  float* __restrict__ stats) {
    int oc  = blockIdx.x;
    int tid = threadIdx.x;
    float s = 0.f, ss = 0.f;
    for (int i = tid; i < PIX; i += 256) {
        int b = i >> 12, hw = i & 4095;
        float v = pre[((size_t)(b * COUT + oc)) * HW + hw];
        s += v; ss += v * v;
    }
    #pragma unroll
    for (int off = 32; off > 0; off >>= 1) {
        s  += __shfl_down(s,  off, 64);
        ss += __shfl_down(ss, off, 64);
    }
    __shared__ float red[8];
    int wid = tid >> 6, lane = tid & 63;
    if (lane == 0) { red[wid] = s; red[4 + wid] = ss; }
    __syncthreads();
    if (tid == 0) {
        float S  = red[0] + red[1] + red[2] + red[3];
        float SS = red[4] + red[5] + red[6] + red[7];
        float mean = S / (float)PIX;
        float var  = SS / (float)PIX - mean * mean;
        stats[oc]       = mean;
        stats[128 + oc] = rsqrtf(var + 1e-5f);
    }
}

// ---------------------------------------------------------------- BN apply + exact GELU (in-place on d_out)
__global__ __launch_bounds__(256) void k_bn_gelu(float* __restrict__ out,
                                                 const float* __restrict__ stats,
                                                 const float* __restrict__ gamma,
                                                 const float* __restrict__ beta) {
    const int n4 = (BB * COUT * HW) / 4;   // 1,048,576 float4
    const float is2 = 0.70710678118654752f;
    for (int i = blockIdx.x * blockDim.x + threadIdx.x; i < n4;
         i += gridDim.x * blockDim.x) {
        int oc = (i >> 10) & 127;          // 1024 float4 per (b,oc) plane
        float g  = gamma[oc] * stats[128 + oc];
        float bt = beta[oc] - stats[oc] * g;
        float4 v = ((const float4*)out)[i];
        float4 r;
        float y;
        y = v.x * g + bt; r.x = 0.5f * y * (1.f + erff(y * is2));
        y = v.y * g + bt; r.y = 0.5f * y * (1.f + erff(y * is2));
        y = v.z * g + bt; r.z = 0.5f * y * (1.f + erff(y * is2));
        y = v.w * g + bt; r.w = 0.5f * y * (1.f + erff(y * is2));
        ((float4*)out)[i] = r;
    }
}

// ---------------------------------------------------------------- launch
extern "C" void kernel_launch(void* const* d_in, const int* in_sizes, int n_in,
                              void* d_out, int out_size, void* d_ws, size_t ws_size,
                              hipStream_t stream) {
    const float* x      = (const float*)d_in[0];
    const float* proj_w = (const float*)d_in[1];
    // d_in[2] = proj_b: per-channel constant, cancels exactly in BatchNorm -> unused
    const float* off_w  = (const float*)d_in[3];
    const float* off_b  = (const float*)d_in[4];
    const float* mod_w  = (const float*)d_in[5];
    const float* mod_b  = (const float*)d_in[6];
    const float* gamma  = (const float*)d_in[7];
    const float* beta   = (const float*)d_in[8];
    float* ws  = (float*)d_ws;
    float* out = (float*)d_out;

    k_transpose  <<<dim3(128, 16, 8), dim3(32, 8), 0, stream>>>(x, ws + OFF_XT);
    k_prep_w     <<<dim3(512), dim3(256), 0, stream>>>(proj_w, off_w, mod_w, ws);
    k_conv27mm   <<<dim3(512), dim3(512), 0, stream>>>(ws + OFF_XT,
                                                       (const unsigned short*)(ws + OFF_A27),
                                                       ws + OFF_PARTIAL);
    k_deform_proj<<<dim3(256), dim3(512), 0, stream>>>(ws + OFF_XT, ws + OFF_PARTIAL,
                                                       off_b, mod_b,
                                                       (const unsigned short*)(ws + OFF_IMG), out);
    k_bn_stats   <<<dim3(128), dim3(256), 0, stream>>>(out, ws + OFF_STATS);
    k_bn_gelu    <<<dim3(2048), dim3(256), 0, stream>>>(out, ws + OFF_STATS, gamma, beta);
}